// Round 19
// baseline (334.864 us; speedup 1.0000x reference)
//
#include <hip/hip_runtime.h>
#include <hip/hip_bf16.h>

// B=4, C=256, C8=32, H=128, W=128, H2=W2=64, N=4096, HW=16384
#define EPS_BN 1e-5f
#define LOG2E 1.4426950408889634f

typedef short bf16x8 __attribute__((ext_vector_type(8)));
typedef float f32x4 __attribute__((ext_vector_type(4)));

__device__ __forceinline__ unsigned short f2bf(float f) {
    __hip_bfloat16 h = __float2bfloat16(f);
    return __builtin_bit_cast(unsigned short, h);
}
__device__ __forceinline__ float bf2f(unsigned short u) {
    return __builtin_bit_cast(float, (unsigned)u << 16);
}
__device__ __forceinline__ void gl_lds16(const void* g, void* l) {
    __builtin_amdgcn_global_load_lds(
        (const __attribute__((address_space(1))) unsigned int*)g,
        (__attribute__((address_space(3))) unsigned int*)l, 16, 0, 0);
}
// raw v_exp_f32 (libm exp2f lowers to slow __ocml wrapper)
__device__ __forceinline__ float fexp2(float x) {
    return __builtin_amdgcn_exp2f(x);
}

// ---------------------------------------------------------------------------
// bf16 MFMA GEMM: Y[b,o,p] = sum_c Wb[o,c] * Xt[b,p,c]  (K=256 fixed)
// BM in {128,64,32}; BN=128; BK=32; 256 threads (4 waves).
// Staging via global_load_lds(16B); LDS rows 64B, slot swizzle at global
// SOURCE (chunk=(l&3)^((l>>3)&3)) and fragment READ (lk^((row>>1)&3)).
// MODE 1: bf16 p-major out (B,P,O) + bias  (q/k merged projection)
// MODE 2: bf16 c-major out (B,256,P) + optional bias (conv1/conv3/v)
// PERM 1: permute p within 64-tiles: p' = (p&~63)|((p&15)*4+((p>>4)&3))
// STATS 1 (MODE 2): per-(block,wc) channel partial sum/sumsq of f32 outputs
// ---------------------------------------------------------------------------
template<int BM, int MODE, int PERM, int STATS>
__global__ __launch_bounds__(256) void gemm_mfma(
    const unsigned short* __restrict__ Wb,   // (O,256) bf16
    const unsigned short* __restrict__ Xt,   // (B,P,256) bf16
    const float* __restrict__ bias,
    unsigned short* __restrict__ Y,
    float* __restrict__ psum, float* __restrict__ psumsq,
    int P, int O)
{
    const int tid = threadIdx.x;
    const int w = tid >> 6, l = tid & 63;
    const int b = blockIdx.z;
    const int p0 = blockIdx.x * 128;
    const int o0 = blockIdx.y * BM;
    const int lr = l & 15, lk = l >> 4;

    __shared__ unsigned short Al[BM * 32];
    __shared__ unsigned short Bl[128 * 32];

    constexpr int WC = (BM == 32) ? 4 : 2;            // waves along p
    constexpr int MT = (BM == 128) ? 4 : 2;           // o-subtiles / wave
    constexpr int NT = (WC == 2) ? 4 : 2;             // p-subtiles / wave
    const int wr = w / WC, wc = w % WC;
    const int osub = wr * MT * 16, psub = wc * NT * 16;

    f32x4 acc[MT][NT];
#pragma unroll
    for (int i = 0; i < MT; i++)
#pragma unroll
        for (int j = 0; j < NT; j++) acc[i][j] = (f32x4){0.f, 0.f, 0.f, 0.f};

    const unsigned short* Xb = Xt + (size_t)b * P * 256;
    const int srow = l >> 2;                         // staged row within wave batch
    const int schunk = (l & 3) ^ ((l >> 3) & 3);     // pre-swizzled source chunk
    const int ar0 = w * 16, ar1 = w * 16 + 64;       // A row batches for this wave
    const int br0 = w * 16, br1 = w * 16 + 64;       // B row batches

    const unsigned short* pB0 = Xb + (size_t)(p0 + br0 + srow) * 256 + schunk * 8;
    const unsigned short* pB1 = Xb + (size_t)(p0 + br1 + srow) * 256 + schunk * 8;
    const unsigned short* pA0 = Wb + (size_t)(o0 + ar0 + srow) * 256 + schunk * 8;
    const unsigned short* pA1 = Wb + (size_t)(o0 + ar1 + srow) * 256 + schunk * 8;
    char* dB0 = (char*)Bl + br0 * 64 + l * 16;
    char* dB1 = (char*)Bl + br1 * 64 + l * 16;
    char* dA0 = (char*)Al + ar0 * 64 + l * 16;
    char* dA1 = (char*)Al + ar1 * 64 + l * 16;

    for (int k0 = 0; k0 < 256; k0 += 32) {
        __syncthreads();   // prior k-step's fragment reads complete
        gl_lds16(pB0, dB0); pB0 += 32;
        gl_lds16(pB1, dB1); pB1 += 32;
        if (ar0 < BM) { gl_lds16(pA0, dA0); pA0 += 32; }
        if (ar1 < BM) { gl_lds16(pA1, dA1); pA1 += 32; }
        __syncthreads();   // vmcnt drain -> staging visible
        bf16x8 af[MT], bfr[NT];
#pragma unroll
        for (int i = 0; i < MT; i++) {
            int row = osub + i * 16 + lr;
            af[i] = *(const bf16x8*)&Al[row * 32 + ((lk ^ ((row >> 1) & 3)) * 8)];
        }
#pragma unroll
        for (int j = 0; j < NT; j++) {
            int row = psub + j * 16 + lr;
            bfr[j] = *(const bf16x8*)&Bl[row * 32 + ((lk ^ ((row >> 1) & 3)) * 8)];
        }
#pragma unroll
        for (int i = 0; i < MT; i++)
#pragma unroll
            for (int j = 0; j < NT; j++)
                acc[i][j] = __builtin_amdgcn_mfma_f32_16x16x32_bf16(af[i], bfr[j], acc[i][j], 0, 0, 0);
    }

    // epilogue; C/D: col = lane&15 (p), row = (lane>>4)*4 + reg (o)
    if (MODE == 1) {
#pragma unroll
        for (int i = 0; i < MT; i++) {
            int ob = o0 + osub + i * 16 + lk * 4;
#pragma unroll
            for (int j = 0; j < NT; j++) {
                int p = p0 + psub + j * 16 + lr;
                ushort4 pk;
                pk.x = f2bf(acc[i][j][0] + bias[ob + 0]);
                pk.y = f2bf(acc[i][j][1] + bias[ob + 1]);
                pk.z = f2bf(acc[i][j][2] + bias[ob + 2]);
                pk.w = f2bf(acc[i][j][3] + bias[ob + 3]);
                *(ushort4*)&Y[((size_t)b * P + p) * O + ob] = pk;
            }
        }
    } else {
#pragma unroll
        for (int i = 0; i < MT; i++)
#pragma unroll
            for (int r = 0; r < 4; r++) {
                int o = o0 + osub + i * 16 + lk * 4 + r;
                float bs = bias ? bias[o] : 0.f;
                float sv = 0.f, sq2 = 0.f;
#pragma unroll
                for (int j = 0; j < NT; j++) {
                    int p = p0 + psub + j * 16 + lr;
                    int p2 = PERM ? ((p & ~63) | ((p & 15) * 4 + ((p >> 4) & 3))) : p;
                    float v = acc[i][j][r] + bs;
                    Y[((size_t)(b * 256 + o)) * P + p2] = f2bf(v);
                    if (STATS) { sv += v; sq2 += v * v; }
                }
                if (STATS) {
#pragma unroll
                    for (int off = 1; off < 16; off <<= 1) {
                        sv += __shfl_xor(sv, off);
                        sq2 += __shfl_xor(sq2, off);
                    }
                    if (lr == 0) {
                        size_t idx = (((size_t)b * 128 + blockIdx.x) * 2 + wc) * 256 + o;
                        psum[idx] = sv;
                        psumsq[idx] = sq2;
                    }
                }
            }
    }
}

// ---------------------------------------------------------------------------
// LDS-tiled transpose + cvt: (B,256,P) f32 -> (B,P,256) bf16
// ---------------------------------------------------------------------------
__global__ __launch_bounds__(256) void transpose_cvt(
    const float* __restrict__ src, unsigned short* __restrict__ dst, int P)
{
    __shared__ float t[64][65];
    const int tid = threadIdx.x;
    const int p0 = blockIdx.x * 64, c0 = blockIdx.y * 64, b = blockIdx.z;
    const float* sb = src + ((size_t)b * 256 + c0) * P + p0;
#pragma unroll
    for (int i = 0; i < 16; i++) {
        int r = (tid >> 6) + 4 * i;   // c-local
        int c = tid & 63;             // p-local
        t[c][r] = sb[(size_t)r * P + c];
    }
    __syncthreads();
#pragma unroll
    for (int i = 0; i < 8; i++) {
        int pr = (tid >> 5) + 8 * i;
        int cc = (tid & 31) * 2;
        unsigned pk = ((unsigned)f2bf(t[pr][cc + 1]) << 16) | f2bf(t[pr][cc]);
        *(unsigned*)&dst[((size_t)b * P + p0 + pr) * 256 + c0 + cc] = pk;
    }
}

// wq/bq pre-scaled by LOG2E so QK^T energies land in log2 domain
__global__ void cvt_weights(const float* __restrict__ w1, const float* __restrict__ wq,
                            const float* __restrict__ wk, const float* __restrict__ wv,
                            const float* __restrict__ w3,
                            const float* __restrict__ bq, const float* __restrict__ bk,
                            unsigned short* o1, unsigned short* oqk,
                            unsigned short* ov, unsigned short* o3, float* obqk)
{
    int i = blockIdx.x * 256 + threadIdx.x;
    if (i < 65536) { o1[i] = f2bf(w1[i]); ov[i] = f2bf(wv[i]); o3[i] = f2bf(w3[i]); }
    if (i < 16384) oqk[i] = f2bf(i < 8192 ? wq[i] * LOG2E : wk[i - 8192]);
    if (i < 64)    obqk[i] = i < 32 ? bq[i] * LOG2E : bk[i - 32];
}

// parallel BN finalize: one BLOCK per channel, strided reduce over NP partials
__global__ __launch_bounds__(256) void bn_finalize_ch(
    const float* __restrict__ psum, const float* __restrict__ psumsq,
    const float* __restrict__ g, const float* __restrict__ bb,
    float* __restrict__ scale, float* __restrict__ shift,
    float invN, int NP)
{
    const int ch = blockIdx.x, t = threadIdx.x;
    float s = 0.f, s2 = 0.f;
    for (int k = t; k < NP; k += 256) {
        s  += psum[(size_t)k * 256 + ch];
        s2 += psumsq[(size_t)k * 256 + ch];
    }
#pragma unroll
    for (int off = 32; off; off >>= 1) {
        s += __shfl_down(s, off); s2 += __shfl_down(s2, off);
    }
    __shared__ float a1[4], a2[4];
    if ((t & 63) == 0) { a1[t >> 6] = s; a2[t >> 6] = s2; }
    __syncthreads();
    if (t == 0) {
        float ts = a1[0] + a1[1] + a1[2] + a1[3];
        float ts2 = a2[0] + a2[1] + a2[2] + a2[3];
        float mean = ts * invN;
        float var  = ts2 * invN - mean * mean;
        float r = rsqrtf(var + EPS_BN);
        float sc = g[ch] * r;
        scale[ch] = sc;
        shift[ch] = bb[ch] - mean * sc;
    }
}

// antialiased bilinear 2x downsample taps (jax.image.resize)
__device__ __forceinline__ int dtaps(int u, int* j, float* w) {
    if (u == 0)  { j[0]=0;   j[1]=1;   j[2]=2;   w[0]=3.f/7.f; w[1]=3.f/7.f; w[2]=1.f/7.f; return 3; }
    if (u == 63) { j[0]=125; j[1]=126; j[2]=127; w[0]=1.f/7.f; w[1]=3.f/7.f; w[2]=3.f/7.f; return 3; }
    j[0]=2*u-1; j[1]=2*u; j[2]=2*u+1; j[3]=2*u+2;
    w[0]=0.125f; w[1]=0.375f; w[2]=0.375f; w[3]=0.125f; return 4;
}

// ---------------------------------------------------------------------------
// BN1 + ReLU + 128->64 downsample FUSED with transpose (round-19; replaces
// bnrelu_down + transpose_bf16 + the hsb buffer).
// y1 bf16 c-major (B,256,16384) -> hst bf16 p-major (B,4096,256).
// grid (64, B), 1024 threads: block = one output row y2 (64 px) x 256 ch.
// Phase 1: thread (og=tid>>6, px=tid&63) computes 16 channels (o=og+16k),
//          coalesced y1 row reads, results to LDS T[px][ch] (pad 258:
//          column writes hit stride-129 banks = 2-way, free).
// Phase 2: coalesced ushort4 writes of full hst rows.
// ---------------------------------------------------------------------------
__global__ __launch_bounds__(1024) void bnrelu_down_t(
    const unsigned short* __restrict__ y1, const float* __restrict__ scale,
    const float* __restrict__ shift, unsigned short* __restrict__ hst)
{
    __shared__ unsigned short T[64][258];
    const int b = blockIdx.y;
    const int y2 = blockIdx.x;           // 0..63
    const int px = threadIdx.x & 63;     // x2
    const int og = threadIdx.x >> 6;     // 0..15 channel subgroup
    int jy[4]; float wy[4]; int ny = dtaps(y2, jy, wy);
    int jx[4]; float wx[4]; int nx = dtaps(px, jx, wx);
#pragma unroll
    for (int k = 0; k < 16; k++) {
        int o = og + k * 16;
        const unsigned short* base = y1 + ((size_t)(b * 256 + o)) * 16384;
        float sc = scale[o], sh = shift[o];
        float acc = 0.f;
        for (int a = 0; a < ny; a++) {
            const unsigned short* row = base + jy[a] * 128;
            for (int c = 0; c < nx; c++) {
                float v = fmaxf(fmaf(sc, bf2f(row[jx[c]]), sh), 0.f);
                acc += wy[a] * wx[c] * v;
            }
        }
        T[px][o] = f2bf(acc);
    }
    __syncthreads();
    unsigned short* dst = hst + ((size_t)b * 4096 + y2 * 64) * 256;
    const int tid = threadIdx.x;
#pragma unroll
    for (int q = 0; q < 4; q++) {
        int lin = q * 4096 + tid * 4;    // element index within 64x256
        int pr = lin >> 8, cc = lin & 255;
        ushort4 pk = { T[pr][cc], T[pr][cc + 1], T[pr][cc + 2], T[pr][cc + 3] };
        *(ushort4*)&dst[lin] = pk;
    }
}

// ---------------------------------------------------------------------------
// Split-K bf16 MFMA flash attention, S=2 chunks of 2048 keys, 128-row Q tiles.
// log2-domain softmax with raw v_exp_f32; defer-max thr 14.4.
// V double-buffered, 1 barrier/tile; vb KEY-PERMUTED so P-writes pack to b64.
// LDS 82KB: Vl 2x32KB slot-XOR swizzled; Pl 18KB pitch-72 shared per wr.
// ---------------------------------------------------------------------------
__global__ __launch_bounds__(512) void attn_partial(
    const unsigned short* __restrict__ qkT, const unsigned short* __restrict__ vb,
    unsigned short* __restrict__ accP, float2* __restrict__ mzP)
{
    const int s = blockIdx.y;
    const int b = blockIdx.z;
    const int i0 = blockIdx.x * 128;
    const int tid = threadIdx.x;
    const int w = tid >> 6, l = tid & 63;
    const int wr = w >> 1, wc = w & 1;
    const int lr = l & 15, lk = l >> 4;

    __shared__ unsigned short Vl[2][256 * 64];    // 64.0 KB double-buffered
    __shared__ unsigned short Pl[4][32 * 72];     // 18.0 KB (pitch 72, shared per wr)

    const unsigned short* qkTb = qkT + (size_t)b * 4096 * 64;
    bf16x8 qf[2];
#pragma unroll
    for (int i = 0; i < 2; i++)
        qf[i] = *(const bf16x8*)&qkTb[(size_t)(i0 + wr * 32 + i * 16 + lr) * 64 + lk * 8];

    f32x4 acc[2][8];
#pragma unroll
    for (int i = 0; i < 2; i++)
#pragma unroll
        for (int c = 0; c < 8; c++) acc[i][c] = (f32x4){0.f, 0.f, 0.f, 0.f};
    float m[2][4], zp[2][4];
#pragma unroll
    for (int i = 0; i < 2; i++)
#pragma unroll
        for (int r = 0; r < 4; r++) { m[i][r] = -1e30f; zp[i][r] = 0.f; }

    const int jbase = s * 2048;
    const unsigned short* kPtr = qkTb + (size_t)(jbase + lr) * 64 + 32 + lk * 8;
    const unsigned short* vPtr =
        vb + (size_t)b * 256 * 4096 + (size_t)(w * 32 + (l >> 3)) * 4096 + jbase + (l & 7) * 8;
    unsigned short* Pw = Pl[wr];
    const int vch = w * 32 + (l >> 3);            // base channel this lane stages
    const int vswz0 = ((l & 7) ^ (vch & 7)) * 8;  // swizzled slot (same for +8k ch)

    uint4 kfr[4], vreg[4];
#pragma unroll
    for (int jt = 0; jt < 4; jt++) kfr[jt] = *(const uint4*)(kPtr + jt * 1024);
    kPtr += 4096;
#pragma unroll
    for (int it = 0; it < 4; it++) vreg[it] = *(const uint4*)(vPtr + it * 32768);
    // stage tile 0 into Vl[0]
#pragma unroll
    for (int it = 0; it < 4; it++)
        *(uint4*)&Vl[0][(vch + it * 8) * 64 + vswz0] = vreg[it];
    __syncthreads();

    for (int t = 0; t < 32; t++) {
        unsigned short* Vc = Vl[t & 1];
        unsigned short* Vn = Vl[(t + 1) & 1];
        if (t < 31) {   // issue next tile's V loads (consumed after PV)
            vPtr += 64;
#pragma unroll
            for (int it = 0; it < 4; it++) vreg[it] = *(const uint4*)(vPtr + it * 32768);
        }

        // per row-subtile: QK^T -> defer-max softmax (log2 domain) -> P write
#pragma unroll
        for (int i = 0; i < 2; i++) {
            f32x4 sv[4];
#pragma unroll
            for (int jt = 0; jt < 4; jt++)
                sv[jt] = __builtin_amdgcn_mfma_f32_16x16x32_bf16(
                    qf[i], __builtin_bit_cast(bf16x8, kfr[jt]), (f32x4){0.f,0.f,0.f,0.f}, 0, 0, 0);
            float tml[4];
            bool trig = false;
#pragma unroll
            for (int r = 0; r < 4; r++) {
                tml[r] = fmaxf(fmaxf(sv[0][r], sv[1][r]), fmaxf(sv[2][r], sv[3][r]));
                trig |= (tml[r] > m[i][r] + 14.4f);
            }
            if (__any(trig)) {   // rare: full reduce + rescale
                float corr[4];
#pragma unroll
                for (int r = 0; r < 4; r++) {
                    float tm = tml[r];
#pragma unroll
                    for (int off = 1; off < 16; off <<= 1) tm = fmaxf(tm, __shfl_xor(tm, off));
                    float mo = m[i][r];
                    float mn = fmaxf(mo, tm);
                    corr[r] = fexp2(mo - mn);
                    m[i][r] = mn;
                    ushort4 pk;
                    float p0 = fexp2(sv[0][r] - mn), p1 = fexp2(sv[1][r] - mn);
                    float p2 = fexp2(sv[2][r] - mn), p3 = fexp2(sv[3][r] - mn);
                    pk.x = f2bf(p0); pk.y = f2bf(p1); pk.z = f2bf(p2); pk.w = f2bf(p3);
                    *(ushort4*)&Pw[(i * 16 + lk * 4 + r) * 72 + lr * 4] = pk;
                    zp[i][r] = zp[i][r] * corr[r] + (p0 + p1) + (p2 + p3);
                }
#pragma unroll
                for (int c = 0; c < 8; c++)
#pragma unroll
                    for (int r = 0; r < 4; r++) acc[i][c][r] *= corr[r];
            } else {             // common: stale max, no shuffles, no rescale
#pragma unroll
                for (int r = 0; r < 4; r++) {
                    float mn = m[i][r];
                    ushort4 pk;
                    float p0 = fexp2(sv[0][r] - mn), p1 = fexp2(sv[1][r] - mn);
                    float p2 = fexp2(sv[2][r] - mn), p3 = fexp2(sv[3][r] - mn);
                    pk.x = f2bf(p0); pk.y = f2bf(p1); pk.z = f2bf(p2); pk.w = f2bf(p3);
                    *(ushort4*)&Pw[(i * 16 + lk * 4 + r) * 72 + lr * 4] = pk;
                    zp[i][r] += (p0 + p1) + (p2 + p3);
                }
            }
        }

        if (t < 31) {   // K prefetch for next tile (after last kfr use)
#pragma unroll
            for (int jt = 0; jt < 4; jt++) kfr[jt] = *(const uint4*)(kPtr + jt * 1024);
            kPtr += 4096;
        }

        // PV: 2 k-chunks x 8 channel subtiles; vf reused across both subtiles
#pragma unroll
        for (int kc = 0; kc < 2; kc++) {
            bf16x8 pa[2];
#pragma unroll
            for (int i = 0; i < 2; i++)
                pa[i] = *(const bf16x8*)&Pw[(i * 16 + lr) * 72 + (kc * 4 + lk) * 8];
#pragma unroll
            for (int ct = 0; ct < 8; ct++) {
                int ch = wc * 128 + ct * 16 + lr;
                bf16x8 vf = *(const bf16x8*)&Vc[ch * 64 + (((kc * 4 + lk) ^ (lr & 7)) * 8)];
#pragma unroll
                for (int i = 0; i < 2; i++)
                    acc[i][ct] = __builtin_amdgcn_mfma_f32_16x16x32_bf16(pa[i], vf, acc[i][ct], 0, 0, 0);
            }
        }

        if (t < 31) {   // stage next tile's V into the other buffer
#pragma unroll
            for (int it = 0; it < 4; it++)
                *(uint4*)&Vn[(vch + it * 8) * 64 + vswz0] = vreg[it];
        }
        __syncthreads();   // Vn visible; all Vc/P reads done before reuse
    }

    // z-reduce over the 16-lane group
    float zs[2][4];
#pragma unroll
    for (int i = 0; i < 2; i++)
#pragma unroll
        for (int r = 0; r < 4; r++) {
            float zz = zp[i][r];
#pragma unroll
            for (int off = 1; off < 16; off <<= 1) zz += __shfl_xor(zz, off);
            zs[i][r] = zz;
        }
    const size_t rbase0 = (size_t)(b * 2 + s) * 4096 + i0;
    if (wc == 0 && lr == 0) {
#pragma unroll
        for (int i = 0; i < 2; i++)
#pragma unroll
            for (int r = 0; r < 4; r++)
                mzP[rbase0 + wr * 32 + i * 16 + lk * 4 + r] = make_float2(m[i][r], zs[i][r]);
    }

    // coalesced bf16 epilogue: TWO 64-row passes through LDS (both V buffers)
    float* Eb = (float*)Vl;   // 16384 f32 = 64 rows x 256 ch
#pragma unroll
    for (int h = 0; h < 2; h++) {
        if ((wr >> 1) == h) {
            int rloc = (wr & 1) * 32;
#pragma unroll
            for (int i = 0; i < 2; i++)
#pragma unroll
                for (int ct = 0; ct < 8; ct++)
#pragma unroll
                    for (int r = 0; r < 4; r++)
                        Eb[(rloc + i * 16 + lk * 4 + r) * 256 + wc * 128 + ct * 16 + lr]
                            = acc[i][ct][r];
        }
        __syncthreads();
        unsigned short* dst = accP + (rbase0 + h * 64) * 256;
#pragma unroll
        for (int q = 0; q < 8; q++) {
            float4 v = ((const float4*)Eb)[tid + q * 512];
            ushort4 pk = { f2bf(v.x), f2bf(v.y), f2bf(v.z), f2bf(v.w) };
            *(ushort4*)&dst[(tid + q * 512) * 4] = pk;
        }
        __syncthreads();
    }
}

// merge S=2 chunk partials + residual -> bf16 h2t, AND emit BN2 partials.
// grid (256, B): 16 rows per block.  (m in log2 domain -> raw exp2 weights)
__global__ __launch_bounds__(256) void attn_combine_stats(
    const unsigned short* __restrict__ accP, const float2* __restrict__ mzP,
    const unsigned short* __restrict__ hst, const float* __restrict__ gamma_p,
    unsigned short* __restrict__ h2tb, float* __restrict__ psum,
    float* __restrict__ psumsq)
{
    const int b = blockIdx.y, ch = threadIdx.x;
    const float gamma = gamma_p[0];
    float s = 0.f, s2 = 0.f;
#pragma unroll 2
    for (int rr = 0; rr < 16; rr++) {
        int row = blockIdx.x * 16 + rr;
        float2 mz[2];
#pragma unroll
        for (int s4 = 0; s4 < 2; s4++) mz[s4] = mzP[(size_t)(b * 2 + s4) * 4096 + row];
        float M = fmaxf(mz[0].x, mz[1].x);
        float Z = 0.f, a = 0.f;
#pragma unroll
        for (int s4 = 0; s4 < 2; s4++) {
            float wgt = fexp2(mz[s4].x - M);
            Z += wgt * mz[s4].y;
            a += wgt * bf2f(accP[((size_t)(b * 2 + s4) * 4096 + row) * 256 + ch]);
        }
        size_t off = ((size_t)b * 4096 + row) * 256 + ch;
        unsigned short hb = f2bf(gamma * a / Z + bf2f(hst[off]));
        h2tb[off] = hb;
        float v = bf2f(hb);
        s += v; s2 += v * v;
    }
    psum[((size_t)b * 256 + blockIdx.x) * 256 + ch] = s;
    psumsq[((size_t)b * 256 + blockIdx.x) * 256 + ch] = s2;
}

// BN2+ReLU fused with bilinear 64->128 upsample; bf16 p-major in/out
// grid (1024, B): 16 pixels per block
__global__ __launch_bounds__(256) void upsample_bnrelu(
    const unsigned short* __restrict__ h2tb, const float* __restrict__ scale,
    const float* __restrict__ shift, unsigned short* __restrict__ upn)
{
    const int b = blockIdx.y, c = threadIdx.x;
    const unsigned short* basep = h2tb + ((size_t)b * 4096) * 256 + c;
    float sc = scale[c], sh = shift[c];
    for (int pp = 0; pp < 16; pp++) {
        int p = blockIdx.x * 16 + pp;
        int y = p >> 7, x = p & 127;
        float fy = 0.5f * y - 0.25f, fx = 0.5f * x - 0.25f;
        float fiy = floorf(fy), fix = floorf(fx);
        float wy = fy - fiy, wx = fx - fix;
        int iy = (int)fiy, ix = (int)fix;
        int iy0 = max(iy, 0), iy1 = min(iy + 1, 63);
        int ix0 = max(ix, 0), ix1 = min(ix + 1, 63);
        float v00 = fmaxf(fmaf(sc, bf2f(basep[(size_t)(iy0 * 64 + ix0) * 256]), sh), 0.f);
        float v01 = fmaxf(fmaf(sc, bf2f(basep[(size_t)(iy0 * 64 + ix1) * 256]), sh), 0.f);
        float v10 = fmaxf(fmaf(sc, bf2f(basep[(size_t)(iy1 * 64 + ix0) * 256]), sh), 0.f);
        float v11 = fmaxf(fmaf(sc, bf2f(basep[(size_t)(iy1 * 64 + ix1) * 256]), sh), 0.f);
        float r0 = (1.f - wy) * ((1.f - wx) * v00 + wx * v01)
                 + wy * ((1.f - wx) * v10 + wx * v11);
        upn[((size_t)b * 16384 + p) * 256 + c] = f2bf(r0);
    }
}

// out = relu(bn3(y3) + x); y3 bf16 c-major
__global__ __launch_bounds__(256) void final_add_relu(
    const unsigned short* __restrict__ y3, const float* __restrict__ scale,
    const float* __restrict__ shift, const float* __restrict__ x,
    float* __restrict__ outp)
{
    size_t e = ((size_t)blockIdx.x * 256 + threadIdx.x) * 4;
    int c = (int)((e >> 14) & 255);
    ushort4 yv = *(const ushort4*)&y3[e];
    float4 xv = *(const float4*)&x[e];
    float sc = scale[c], sh = shift[c];
    float4 o;
    o.x = fmaxf(fmaf(sc, bf2f(yv.x), sh) + xv.x, 0.f);
    o.y = fmaxf(fmaf(sc, bf2f(yv.y), sh) + xv.y, 0.f);
    o.z = fmaxf(fmaf(sc, bf2f(yv.z), sh) + xv.z, 0.f);
    o.w = fmaxf(fmaf(sc, bf2f(yv.w), sh) + xv.w, 0.f);
    *(float4*)&outp[e] = o;
}

extern "C" void kernel_launch(void* const* d_in, const int* in_sizes, int n_in,
                              void* d_out, int out_size, void* d_ws, size_t ws_size,
                              hipStream_t stream)
{
    const float* x     = (const float*)d_in[0];
    const float* w1    = (const float*)d_in[1];
    const float* g1    = (const float*)d_in[2];
    const float* b1    = (const float*)d_in[3];
    const float* wq    = (const float*)d_in[4];
    const float* bq    = (const float*)d_in[5];
    const float* wk    = (const float*)d_in[6];
    const float* bk    = (const float*)d_in[7];
    const float* wv    = (const float*)d_in[8];
    const float* bv    = (const float*)d_in[9];
    const float* gamma = (const float*)d_in[10];
    const float* g2    = (const float*)d_in[11];
    const float* b2    = (const float*)d_in[12];
    const float* w3    = (const float*)d_in[13];
    const float* g3    = (const float*)d_in[14];
    const float* b3    = (const float*)d_in[15];
    float* out = (float*)d_out;

    char* wsb = (char*)d_ws;
    unsigned short* y1b = (unsigned short*)wsb;                        // 0-32 (later y3b)
    unsigned short* xt  = (unsigned short*)(wsb + ((size_t)32 << 20)); // 32-64 (later upn)
    unsigned short* accPb = (unsigned short*)wsb;                      // 0-16 during attn (bf16)
    unsigned short* h2tb = (unsigned short*)(wsb + ((size_t)64 << 20));// 64-72
    float* psum2   = (float*)(wsb + ((size_t)72 << 20));               // 72-73 (BN2 partials)
    float* psumsq2 = (float*)(wsb + ((size_t)73 << 20));               // 73-74
    unsigned short* vbb = (unsigned short*)(wsb + ((size_t)82 << 20)); // 82-90 (key-permuted)
    unsigned short* hst = (unsigned short*)(wsb + ((size_t)90 << 20)); // 90-98
    unsigned short* qkT = (unsigned short*)(wsb + ((size_t)98 << 20)); // 98-100
    unsigned short* w1b = (unsigned short*)(wsb + ((size_t)100 << 20));
    unsigned short* wvb  = w1b + 65536;
    unsigned short* w3b  = wvb + 65536;
    unsigned short* wqkb = w3b + 65536;
    float* bqk = (float*)(wqkb + 16384);
    float2* mzP = (float2*)(wsb + ((size_t)100 << 20) + ((size_t)512 << 10));
    float* psumC   = (float*)(wsb + ((size_t)102 << 20));              // 102-103 (conv stats)
    float* psumsqC = (float*)(wsb + ((size_t)103 << 20));              // 103-104
    float* sc1 = (float*)(wsb + ((size_t)104 << 20)); float* sh1 = sc1 + 256;
    float* sc2 = sh1 + 256;      float* sh2 = sc2 + 256;
    float* sc3 = sh2 + 256;      float* sh3 = sc3 + 256;
    unsigned short* y3b = y1b;
    unsigned short* upn = xt;

    cvt_weights<<<256, 256, 0, stream>>>(w1, wq, wk, wv, w3, bq, bk,
                                         w1b, wqkb, wvb, w3b, bqk);
    transpose_cvt<<<dim3(256, 4, 4), 256, 0, stream>>>(x, xt, 16384);

    // net1: conv1 (MFMA, gl_lds staging, stats fused) -> BN1 ->
    //       fused BN+ReLU+down+transpose (writes hst p-major directly)
    gemm_mfma<128, 2, 0, 1><<<dim3(128, 2, 4), 256, 0, stream>>>(
        w1b, xt, nullptr, y1b, psumC, psumsqC, 16384, 256);
    bn_finalize_ch<<<256, 256, 0, stream>>>(psumC, psumsqC, g1, b1, sc1, sh1,
                                            1.f / 65536.f, 1024);
    bnrelu_down_t<<<dim3(64, 4), 1024, 0, stream>>>(y1b, sc1, sh1, hst);

    // net2: merged qk projection + permuted v projection + split-K attention
    gemm_mfma<64, 1, 0, 0><<<dim3(32, 1, 4), 256, 0, stream>>>(
        wqkb, hst, bqk, qkT, nullptr, nullptr, 4096, 64);
    gemm_mfma<128, 2, 1, 0><<<dim3(32, 2, 4), 256, 0, stream>>>(
        wvb, hst, bv, vbb, nullptr, nullptr, 4096, 256);
    attn_partial<<<dim3(32, 2, 4), 512, 0, stream>>>(qkT, vbb, accPb, mzP);
    attn_combine_stats<<<dim3(256, 4), 256, 0, stream>>>(accPb, mzP, hst, gamma,
                                                         h2tb, psum2, psumsq2);

    // net2 tail: BN2 finalize (parallel) + ReLU fused into upsample
    bn_finalize_ch<<<256, 256, 0, stream>>>(psum2, psumsq2, g2, b2, sc2, sh2,
                                            1.f / 16384.f, 1024);
    upsample_bnrelu<<<dim3(1024, 4), 256, 0, stream>>>(h2tb, sc2, sh2, upn);

    // net3: conv3 (MFMA, gl_lds staging, stats fused) -> BN3 -> residual + ReLU
    gemm_mfma<128, 2, 0, 1><<<dim3(128, 2, 4), 256, 0, stream>>>(
        w3b, upn, nullptr, y3b, psumC, psumsqC, 16384, 256);
    bn_finalize_ch<<<256, 256, 0, stream>>>(psumC, psumsqC, g3, b3, sc3, sh3,
                                            1.f / 65536.f, 1024);
    final_add_relu<<<16384, 256, 0, stream>>>(y3b, sc3, sh3, x, out);
}

// Round 20
// 322.270 us; speedup vs baseline: 1.0391x; 1.0391x over previous
//
#include <hip/hip_runtime.h>
#include <hip/hip_bf16.h>

// B=4, C=256, C8=32, H=128, W=128, H2=W2=64, N=4096, HW=16384
#define EPS_BN 1e-5f
#define LOG2E 1.4426950408889634f

typedef short bf16x8 __attribute__((ext_vector_type(8)));
typedef float f32x4 __attribute__((ext_vector_type(4)));

__device__ __forceinline__ unsigned short f2bf(float f) {
    __hip_bfloat16 h = __float2bfloat16(f);
    return __builtin_bit_cast(unsigned short, h);
}
__device__ __forceinline__ float bf2f(unsigned short u) {
    return __builtin_bit_cast(float, (unsigned)u << 16);
}
__device__ __forceinline__ void gl_lds16(const void* g, void* l) {
    __builtin_amdgcn_global_load_lds(
        (const __attribute__((address_space(1))) unsigned int*)g,
        (__attribute__((address_space(3))) unsigned int*)l, 16, 0, 0);
}
// raw v_exp_f32 (libm exp2f lowers to slow __ocml wrapper)
__device__ __forceinline__ float fexp2(float x) {
    return __builtin_amdgcn_exp2f(x);
}

// ---------------------------------------------------------------------------
// bf16 MFMA GEMM: Y[b,o,p] = sum_c Wb[o,c] * Xt[b,p,c]  (K=256 fixed)
// BM in {128,64,32}; BN=128; BK=32; 256 threads (4 waves).
// Staging via global_load_lds(16B); LDS rows 64B, slot swizzle at global
// SOURCE (chunk=(l&3)^((l>>3)&3)) and fragment READ (lk^((row>>1)&3)).
// MODE 1: bf16 p-major out (B,P,O) + bias  (q/k merged projection)
// MODE 2: bf16 c-major out (B,256,P) + optional bias (conv1/conv3/v)
// PERM 1: permute p within 64-tiles: p' = (p&~63)|((p&15)*4+((p>>4)&3))
// STATS 1 (MODE 2): per-(block,wc) channel partial sum/sumsq of f32 outputs
// ---------------------------------------------------------------------------
template<int BM, int MODE, int PERM, int STATS>
__global__ __launch_bounds__(256) void gemm_mfma(
    const unsigned short* __restrict__ Wb,   // (O,256) bf16
    const unsigned short* __restrict__ Xt,   // (B,P,256) bf16
    const float* __restrict__ bias,
    unsigned short* __restrict__ Y,
    float* __restrict__ psum, float* __restrict__ psumsq,
    int P, int O)
{
    const int tid = threadIdx.x;
    const int w = tid >> 6, l = tid & 63;
    const int b = blockIdx.z;
    const int p0 = blockIdx.x * 128;
    const int o0 = blockIdx.y * BM;
    const int lr = l & 15, lk = l >> 4;

    __shared__ unsigned short Al[BM * 32];
    __shared__ unsigned short Bl[128 * 32];

    constexpr int WC = (BM == 32) ? 4 : 2;            // waves along p
    constexpr int MT = (BM == 128) ? 4 : 2;           // o-subtiles / wave
    constexpr int NT = (WC == 2) ? 4 : 2;             // p-subtiles / wave
    const int wr = w / WC, wc = w % WC;
    const int osub = wr * MT * 16, psub = wc * NT * 16;

    f32x4 acc[MT][NT];
#pragma unroll
    for (int i = 0; i < MT; i++)
#pragma unroll
        for (int j = 0; j < NT; j++) acc[i][j] = (f32x4){0.f, 0.f, 0.f, 0.f};

    const unsigned short* Xb = Xt + (size_t)b * P * 256;
    const int srow = l >> 2;                         // staged row within wave batch
    const int schunk = (l & 3) ^ ((l >> 3) & 3);     // pre-swizzled source chunk
    const int ar0 = w * 16, ar1 = w * 16 + 64;       // A row batches for this wave
    const int br0 = w * 16, br1 = w * 16 + 64;       // B row batches

    const unsigned short* pB0 = Xb + (size_t)(p0 + br0 + srow) * 256 + schunk * 8;
    const unsigned short* pB1 = Xb + (size_t)(p0 + br1 + srow) * 256 + schunk * 8;
    const unsigned short* pA0 = Wb + (size_t)(o0 + ar0 + srow) * 256 + schunk * 8;
    const unsigned short* pA1 = Wb + (size_t)(o0 + ar1 + srow) * 256 + schunk * 8;
    char* dB0 = (char*)Bl + br0 * 64 + l * 16;
    char* dB1 = (char*)Bl + br1 * 64 + l * 16;
    char* dA0 = (char*)Al + ar0 * 64 + l * 16;
    char* dA1 = (char*)Al + ar1 * 64 + l * 16;

    for (int k0 = 0; k0 < 256; k0 += 32) {
        __syncthreads();   // prior k-step's fragment reads complete
        gl_lds16(pB0, dB0); pB0 += 32;
        gl_lds16(pB1, dB1); pB1 += 32;
        if (ar0 < BM) { gl_lds16(pA0, dA0); pA0 += 32; }
        if (ar1 < BM) { gl_lds16(pA1, dA1); pA1 += 32; }
        __syncthreads();   // vmcnt drain -> staging visible
        bf16x8 af[MT], bfr[NT];
#pragma unroll
        for (int i = 0; i < MT; i++) {
            int row = osub + i * 16 + lr;
            af[i] = *(const bf16x8*)&Al[row * 32 + ((lk ^ ((row >> 1) & 3)) * 8)];
        }
#pragma unroll
        for (int j = 0; j < NT; j++) {
            int row = psub + j * 16 + lr;
            bfr[j] = *(const bf16x8*)&Bl[row * 32 + ((lk ^ ((row >> 1) & 3)) * 8)];
        }
#pragma unroll
        for (int i = 0; i < MT; i++)
#pragma unroll
            for (int j = 0; j < NT; j++)
                acc[i][j] = __builtin_amdgcn_mfma_f32_16x16x32_bf16(af[i], bfr[j], acc[i][j], 0, 0, 0);
    }

    // epilogue; C/D: col = lane&15 (p), row = (lane>>4)*4 + reg (o)
    if (MODE == 1) {
#pragma unroll
        for (int i = 0; i < MT; i++) {
            int ob = o0 + osub + i * 16 + lk * 4;
#pragma unroll
            for (int j = 0; j < NT; j++) {
                int p = p0 + psub + j * 16 + lr;
                ushort4 pk;
                pk.x = f2bf(acc[i][j][0] + bias[ob + 0]);
                pk.y = f2bf(acc[i][j][1] + bias[ob + 1]);
                pk.z = f2bf(acc[i][j][2] + bias[ob + 2]);
                pk.w = f2bf(acc[i][j][3] + bias[ob + 3]);
                *(ushort4*)&Y[((size_t)b * P + p) * O + ob] = pk;
            }
        }
    } else {
#pragma unroll
        for (int i = 0; i < MT; i++)
#pragma unroll
            for (int r = 0; r < 4; r++) {
                int o = o0 + osub + i * 16 + lk * 4 + r;
                float bs = bias ? bias[o] : 0.f;
                float sv = 0.f, sq2 = 0.f;
#pragma unroll
                for (int j = 0; j < NT; j++) {
                    int p = p0 + psub + j * 16 + lr;
                    int p2 = PERM ? ((p & ~63) | ((p & 15) * 4 + ((p >> 4) & 3))) : p;
                    float v = acc[i][j][r] + bs;
                    Y[((size_t)(b * 256 + o)) * P + p2] = f2bf(v);
                    if (STATS) { sv += v; sq2 += v * v; }
                }
                if (STATS) {
#pragma unroll
                    for (int off = 1; off < 16; off <<= 1) {
                        sv += __shfl_xor(sv, off);
                        sq2 += __shfl_xor(sq2, off);
                    }
                    if (lr == 0) {
                        size_t idx = (((size_t)b * 128 + blockIdx.x) * 2 + wc) * 256 + o;
                        psum[idx] = sv;
                        psumsq[idx] = sq2;
                    }
                }
            }
    }
}

// ---------------------------------------------------------------------------
// LDS-tiled transpose + cvt: (B,256,P) f32 -> (B,P,256) bf16
// ---------------------------------------------------------------------------
__global__ __launch_bounds__(256) void transpose_cvt(
    const float* __restrict__ src, unsigned short* __restrict__ dst, int P)
{
    __shared__ float t[64][65];
    const int tid = threadIdx.x;
    const int p0 = blockIdx.x * 64, c0 = blockIdx.y * 64, b = blockIdx.z;
    const float* sb = src + ((size_t)b * 256 + c0) * P + p0;
#pragma unroll
    for (int i = 0; i < 16; i++) {
        int r = (tid >> 6) + 4 * i;   // c-local
        int c = tid & 63;             // p-local
        t[c][r] = sb[(size_t)r * P + c];
    }
    __syncthreads();
#pragma unroll
    for (int i = 0; i < 8; i++) {
        int pr = (tid >> 5) + 8 * i;
        int cc = (tid & 31) * 2;
        unsigned pk = ((unsigned)f2bf(t[pr][cc + 1]) << 16) | f2bf(t[pr][cc]);
        *(unsigned*)&dst[((size_t)b * P + p0 + pr) * 256 + c0 + cc] = pk;
    }
}

// bf16 -> bf16 transpose: (B,256,P) -> (B,P,256)
__global__ __launch_bounds__(256) void transpose_bf16(
    const unsigned short* __restrict__ src, unsigned short* __restrict__ dst, int P)
{
    __shared__ unsigned short t[64][66];
    const int tid = threadIdx.x;
    const int p0 = blockIdx.x * 64, c0 = blockIdx.y * 64, b = blockIdx.z;
    const unsigned short* sb = src + ((size_t)b * 256 + c0) * P + p0;
#pragma unroll
    for (int i = 0; i < 16; i++) {
        int r = (tid >> 6) + 4 * i;   // c-local
        int c = tid & 63;             // p-local
        t[c][r] = sb[(size_t)r * P + c];
    }
    __syncthreads();
#pragma unroll
    for (int i = 0; i < 8; i++) {
        int pr = (tid >> 5) + 8 * i;
        int cc = (tid & 31) * 2;
        unsigned pk = ((unsigned)t[pr][cc + 1] << 16) | t[pr][cc];
        *(unsigned*)&dst[((size_t)b * P + p0 + pr) * 256 + c0 + cc] = pk;
    }
}

// wq/bq pre-scaled by LOG2E so QK^T energies land in log2 domain
__global__ void cvt_weights(const float* __restrict__ w1, const float* __restrict__ wq,
                            const float* __restrict__ wk, const float* __restrict__ wv,
                            const float* __restrict__ w3,
                            const float* __restrict__ bq, const float* __restrict__ bk,
                            unsigned short* o1, unsigned short* oqk,
                            unsigned short* ov, unsigned short* o3, float* obqk)
{
    int i = blockIdx.x * 256 + threadIdx.x;
    if (i < 65536) { o1[i] = f2bf(w1[i]); ov[i] = f2bf(wv[i]); o3[i] = f2bf(w3[i]); }
    if (i < 16384) oqk[i] = f2bf(i < 8192 ? wq[i] * LOG2E : wk[i - 8192]);
    if (i < 64)    obqk[i] = i < 32 ? bq[i] * LOG2E : bk[i - 32];
}

// parallel BN finalize: one BLOCK per channel, strided reduce over NP partials
__global__ __launch_bounds__(256) void bn_finalize_ch(
    const float* __restrict__ psum, const float* __restrict__ psumsq,
    const float* __restrict__ g, const float* __restrict__ bb,
    float* __restrict__ scale, float* __restrict__ shift,
    float invN, int NP)
{
    const int ch = blockIdx.x, t = threadIdx.x;
    float s = 0.f, s2 = 0.f;
    for (int k = t; k < NP; k += 256) {
        s  += psum[(size_t)k * 256 + ch];
        s2 += psumsq[(size_t)k * 256 + ch];
    }
#pragma unroll
    for (int off = 32; off; off >>= 1) {
        s += __shfl_down(s, off); s2 += __shfl_down(s2, off);
    }
    __shared__ float a1[4], a2[4];
    if ((t & 63) == 0) { a1[t >> 6] = s; a2[t >> 6] = s2; }
    __syncthreads();
    if (t == 0) {
        float ts = a1[0] + a1[1] + a1[2] + a1[3];
        float ts2 = a2[0] + a2[1] + a2[2] + a2[3];
        float mean = ts * invN;
        float var  = ts2 * invN - mean * mean;
        float r = rsqrtf(var + EPS_BN);
        float sc = g[ch] * r;
        scale[ch] = sc;
        shift[ch] = bb[ch] - mean * sc;
    }
}

// antialiased bilinear 2x downsample taps (jax.image.resize)
__device__ __forceinline__ int dtaps(int u, int* j, float* w) {
    if (u == 0)  { j[0]=0;   j[1]=1;   j[2]=2;   w[0]=3.f/7.f; w[1]=3.f/7.f; w[2]=1.f/7.f; return 3; }
    if (u == 63) { j[0]=125; j[1]=126; j[2]=127; w[0]=1.f/7.f; w[1]=3.f/7.f; w[2]=3.f/7.f; return 3; }
    j[0]=2*u-1; j[1]=2*u; j[2]=2*u+1; j[3]=2*u+2;
    w[0]=0.125f; w[1]=0.375f; w[2]=0.375f; w[3]=0.125f; return 4;
}

// BN + ReLU + 128->64 downsample; y1 bf16 c-major in, hs bf16 c-major out
__global__ __launch_bounds__(256) void bnrelu_down(
    const unsigned short* __restrict__ y1, const float* __restrict__ scale,
    const float* __restrict__ shift, unsigned short* __restrict__ h)
{
    int i = blockIdx.x * 256 + threadIdx.x;  // 0..4095 over 64x64
    int o = blockIdx.y, b = blockIdx.z;
    int y2 = i >> 6, x2 = i & 63;
    const unsigned short* base = y1 + ((size_t)(b * 256 + o)) * 16384;
    float sc = scale[o], sh = shift[o];
    int jy[4]; float wy[4]; int ny = dtaps(y2, jy, wy);
    int jx[4]; float wx[4]; int nx = dtaps(x2, jx, wx);
    float acc = 0.f;
    for (int a = 0; a < ny; a++) {
        const unsigned short* row = base + jy[a] * 128;
        for (int c = 0; c < nx; c++) {
            float v = fmaxf(fmaf(sc, bf2f(row[jx[c]]), sh), 0.f);
            acc += wy[a] * wx[c] * v;
        }
    }
    h[((size_t)(b * 256 + o)) * 4096 + i] = f2bf(acc);
}

// ---------------------------------------------------------------------------
// Split-K bf16 MFMA flash attention, S=2 chunks of 2048 keys, 128-row Q tiles.
// log2-domain softmax with raw v_exp_f32; defer-max thr 14.4.
// V double-buffered, 1 barrier/tile; vb KEY-PERMUTED so P-writes pack to b64.
// Epilogue in 2 passes using BOTH V buffers as a 64-row f32 bounce.
// LDS 82KB: Vl 2x32KB slot-XOR swizzled; Pl 18KB pitch-72 shared per wr.
// ---------------------------------------------------------------------------
__global__ __launch_bounds__(512) void attn_partial(
    const unsigned short* __restrict__ qkT, const unsigned short* __restrict__ vb,
    unsigned short* __restrict__ accP, float2* __restrict__ mzP)
{
    const int s = blockIdx.y;
    const int b = blockIdx.z;
    const int i0 = blockIdx.x * 128;
    const int tid = threadIdx.x;
    const int w = tid >> 6, l = tid & 63;
    const int wr = w >> 1, wc = w & 1;
    const int lr = l & 15, lk = l >> 4;

    __shared__ unsigned short Vl[2][256 * 64];    // 64.0 KB double-buffered
    __shared__ unsigned short Pl[4][32 * 72];     // 18.0 KB (pitch 72, shared per wr)

    const unsigned short* qkTb = qkT + (size_t)b * 4096 * 64;
    bf16x8 qf[2];
#pragma unroll
    for (int i = 0; i < 2; i++)
        qf[i] = *(const bf16x8*)&qkTb[(size_t)(i0 + wr * 32 + i * 16 + lr) * 64 + lk * 8];

    f32x4 acc[2][8];
#pragma unroll
    for (int i = 0; i < 2; i++)
#pragma unroll
        for (int c = 0; c < 8; c++) acc[i][c] = (f32x4){0.f, 0.f, 0.f, 0.f};
    float m[2][4], zp[2][4];
#pragma unroll
    for (int i = 0; i < 2; i++)
#pragma unroll
        for (int r = 0; r < 4; r++) { m[i][r] = -1e30f; zp[i][r] = 0.f; }

    const int jbase = s * 2048;
    const unsigned short* kPtr = qkTb + (size_t)(jbase + lr) * 64 + 32 + lk * 8;
    const unsigned short* vPtr =
        vb + (size_t)b * 256 * 4096 + (size_t)(w * 32 + (l >> 3)) * 4096 + jbase + (l & 7) * 8;
    unsigned short* Pw = Pl[wr];
    const int vch = w * 32 + (l >> 3);            // base channel this lane stages
    const int vswz0 = ((l & 7) ^ (vch & 7)) * 8;  // swizzled slot (same for +8k ch)

    uint4 kfr[4], vreg[4];
#pragma unroll
    for (int jt = 0; jt < 4; jt++) kfr[jt] = *(const uint4*)(kPtr + jt * 1024);
    kPtr += 4096;
#pragma unroll
    for (int it = 0; it < 4; it++) vreg[it] = *(const uint4*)(vPtr + it * 32768);
    // stage tile 0 into Vl[0]
#pragma unroll
    for (int it = 0; it < 4; it++)
        *(uint4*)&Vl[0][(vch + it * 8) * 64 + vswz0] = vreg[it];
    __syncthreads();

    for (int t = 0; t < 32; t++) {
        unsigned short* Vc = Vl[t & 1];
        unsigned short* Vn = Vl[(t + 1) & 1];
        if (t < 31) {   // issue next tile's V loads (consumed after PV)
            vPtr += 64;
#pragma unroll
            for (int it = 0; it < 4; it++) vreg[it] = *(const uint4*)(vPtr + it * 32768);
        }

        // per row-subtile: QK^T -> defer-max softmax (log2 domain) -> P write
#pragma unroll
        for (int i = 0; i < 2; i++) {
            f32x4 sv[4];
#pragma unroll
            for (int jt = 0; jt < 4; jt++)
                sv[jt] = __builtin_amdgcn_mfma_f32_16x16x32_bf16(
                    qf[i], __builtin_bit_cast(bf16x8, kfr[jt]), (f32x4){0.f,0.f,0.f,0.f}, 0, 0, 0);
            float tml[4];
            bool trig = false;
#pragma unroll
            for (int r = 0; r < 4; r++) {
                tml[r] = fmaxf(fmaxf(sv[0][r], sv[1][r]), fmaxf(sv[2][r], sv[3][r]));
                trig |= (tml[r] > m[i][r] + 14.4f);
            }
            if (__any(trig)) {   // rare: full reduce + rescale
                float corr[4];
#pragma unroll
                for (int r = 0; r < 4; r++) {
                    float tm = tml[r];
#pragma unroll
                    for (int off = 1; off < 16; off <<= 1) tm = fmaxf(tm, __shfl_xor(tm, off));
                    float mo = m[i][r];
                    float mn = fmaxf(mo, tm);
                    corr[r] = fexp2(mo - mn);
                    m[i][r] = mn;
                    ushort4 pk;
                    float p0 = fexp2(sv[0][r] - mn), p1 = fexp2(sv[1][r] - mn);
                    float p2 = fexp2(sv[2][r] - mn), p3 = fexp2(sv[3][r] - mn);
                    pk.x = f2bf(p0); pk.y = f2bf(p1); pk.z = f2bf(p2); pk.w = f2bf(p3);
                    *(ushort4*)&Pw[(i * 16 + lk * 4 + r) * 72 + lr * 4] = pk;
                    zp[i][r] = zp[i][r] * corr[r] + (p0 + p1) + (p2 + p3);
                }
#pragma unroll
                for (int c = 0; c < 8; c++)
#pragma unroll
                    for (int r = 0; r < 4; r++) acc[i][c][r] *= corr[r];
            } else {             // common: stale max, no shuffles, no rescale
#pragma unroll
                for (int r = 0; r < 4; r++) {
                    float mn = m[i][r];
                    ushort4 pk;
                    float p0 = fexp2(sv[0][r] - mn), p1 = fexp2(sv[1][r] - mn);
                    float p2 = fexp2(sv[2][r] - mn), p3 = fexp2(sv[3][r] - mn);
                    pk.x = f2bf(p0); pk.y = f2bf(p1); pk.z = f2bf(p2); pk.w = f2bf(p3);
                    *(ushort4*)&Pw[(i * 16 + lk * 4 + r) * 72 + lr * 4] = pk;
                    zp[i][r] += (p0 + p1) + (p2 + p3);
                }
            }
        }

        if (t < 31) {   // K prefetch for next tile (after last kfr use)
#pragma unroll
            for (int jt = 0; jt < 4; jt++) kfr[jt] = *(const uint4*)(kPtr + jt * 1024);
            kPtr += 4096;
        }

        // PV: 2 k-chunks x 8 channel subtiles; vf reused across both subtiles
#pragma unroll
        for (int kc = 0; kc < 2; kc++) {
            bf16x8 pa[2];
#pragma unroll
            for (int i = 0; i < 2; i++)
                pa[i] = *(const bf16x8*)&Pw[(i * 16 + lr) * 72 + (kc * 4 + lk) * 8];
#pragma unroll
            for (int ct = 0; ct < 8; ct++) {
                int ch = wc * 128 + ct * 16 + lr;
                bf16x8 vf = *(const bf16x8*)&Vc[ch * 64 + (((kc * 4 + lk) ^ (lr & 7)) * 8)];
#pragma unroll
                for (int i = 0; i < 2; i++)
                    acc[i][ct] = __builtin_amdgcn_mfma_f32_16x16x32_bf16(pa[i], vf, acc[i][ct], 0, 0, 0);
            }
        }

        if (t < 31) {   // stage next tile's V into the other buffer
#pragma unroll
            for (int it = 0; it < 4; it++)
                *(uint4*)&Vn[(vch + it * 8) * 64 + vswz0] = vreg[it];
        }
        __syncthreads();   // Vn visible; all Vc/P reads done before reuse
    }

    // z-reduce over the 16-lane group
    float zs[2][4];
#pragma unroll
    for (int i = 0; i < 2; i++)
#pragma unroll
        for (int r = 0; r < 4; r++) {
            float zz = zp[i][r];
#pragma unroll
            for (int off = 1; off < 16; off <<= 1) zz += __shfl_xor(zz, off);
            zs[i][r] = zz;
        }
    const size_t rbase0 = (size_t)(b * 2 + s) * 4096 + i0;
    if (wc == 0 && lr == 0) {
#pragma unroll
        for (int i = 0; i < 2; i++)
#pragma unroll
            for (int r = 0; r < 4; r++)
                mzP[rbase0 + wr * 32 + i * 16 + lk * 4 + r] = make_float2(m[i][r], zs[i][r]);
    }

    // coalesced bf16 epilogue: TWO 64-row passes through LDS (both V buffers)
    float* Eb = (float*)Vl;   // 16384 f32 = 64 rows x 256 ch
#pragma unroll
    for (int h = 0; h < 2; h++) {
        if ((wr >> 1) == h) {
            int rloc = (wr & 1) * 32;
#pragma unroll
            for (int i = 0; i < 2; i++)
#pragma unroll
                for (int ct = 0; ct < 8; ct++)
#pragma unroll
                    for (int r = 0; r < 4; r++)
                        Eb[(rloc + i * 16 + lk * 4 + r) * 256 + wc * 128 + ct * 16 + lr]
                            = acc[i][ct][r];
        }
        __syncthreads();
        unsigned short* dst = accP + (rbase0 + h * 64) * 256;
#pragma unroll
        for (int q = 0; q < 8; q++) {
            float4 v = ((const float4*)Eb)[tid + q * 512];
            ushort4 pk = { f2bf(v.x), f2bf(v.y), f2bf(v.z), f2bf(v.w) };
            *(ushort4*)&dst[(tid + q * 512) * 4] = pk;
        }
        __syncthreads();
    }
}

// merge S=2 chunk partials + residual -> bf16 h2t, AND emit BN2 partials.
// grid (256, B): 16 rows per block.  (m in log2 domain -> raw exp2 weights)
__global__ __launch_bounds__(256) void attn_combine_stats(
    const unsigned short* __restrict__ accP, const float2* __restrict__ mzP,
    const unsigned short* __restrict__ hst, const float* __restrict__ gamma_p,
    unsigned short* __restrict__ h2tb, float* __restrict__ psum,
    float* __restrict__ psumsq)
{
    const int b = blockIdx.y, ch = threadIdx.x;
    const float gamma = gamma_p[0];
    float s = 0.f, s2 = 0.f;
#pragma unroll 2
    for (int rr = 0; rr < 16; rr++) {
        int row = blockIdx.x * 16 + rr;
        float2 mz[2];
#pragma unroll
        for (int s4 = 0; s4 < 2; s4++) mz[s4] = mzP[(size_t)(b * 2 + s4) * 4096 + row];
        float M = fmaxf(mz[0].x, mz[1].x);
        float Z = 0.f, a = 0.f;
#pragma unroll
        for (int s4 = 0; s4 < 2; s4++) {
            float wgt = fexp2(mz[s4].x - M);
            Z += wgt * mz[s4].y;
            a += wgt * bf2f(accP[((size_t)(b * 2 + s4) * 4096 + row) * 256 + ch]);
        }
        size_t off = ((size_t)b * 4096 + row) * 256 + ch;
        unsigned short hb = f2bf(gamma * a / Z + bf2f(hst[off]));
        h2tb[off] = hb;
        float v = bf2f(hb);
        s += v; s2 += v * v;
    }
    psum[((size_t)b * 256 + blockIdx.x) * 256 + ch] = s;
    psumsq[((size_t)b * 256 + blockIdx.x) * 256 + ch] = s2;
}

// BN2+ReLU fused with bilinear 64->128 upsample; bf16 p-major in/out
// grid (1024, B): 16 pixels per block
__global__ __launch_bounds__(256) void upsample_bnrelu(
    const unsigned short* __restrict__ h2tb, const float* __restrict__ scale,
    const float* __restrict__ shift, unsigned short* __restrict__ upn)
{
    const int b = blockIdx.y, c = threadIdx.x;
    const unsigned short* basep = h2tb + ((size_t)b * 4096) * 256 + c;
    float sc = scale[c], sh = shift[c];
    for (int pp = 0; pp < 16; pp++) {
        int p = blockIdx.x * 16 + pp;
        int y = p >> 7, x = p & 127;
        float fy = 0.5f * y - 0.25f, fx = 0.5f * x - 0.25f;
        float fiy = floorf(fy), fix = floorf(fx);
        float wy = fy - fiy, wx = fx - fix;
        int iy = (int)fiy, ix = (int)fix;
        int iy0 = max(iy, 0), iy1 = min(iy + 1, 63);
        int ix0 = max(ix, 0), ix1 = min(ix + 1, 63);
        float v00 = fmaxf(fmaf(sc, bf2f(basep[(size_t)(iy0 * 64 + ix0) * 256]), sh), 0.f);
        float v01 = fmaxf(fmaf(sc, bf2f(basep[(size_t)(iy0 * 64 + ix1) * 256]), sh), 0.f);
        float v10 = fmaxf(fmaf(sc, bf2f(basep[(size_t)(iy1 * 64 + ix0) * 256]), sh), 0.f);
        float v11 = fmaxf(fmaf(sc, bf2f(basep[(size_t)(iy1 * 64 + ix1) * 256]), sh), 0.f);
        float r0 = (1.f - wy) * ((1.f - wx) * v00 + wx * v01)
                 + wy * ((1.f - wx) * v10 + wx * v11);
        upn[((size_t)b * 16384 + p) * 256 + c] = f2bf(r0);
    }
}

// out = relu(bn3(y3) + x); y3 bf16 c-major
__global__ __launch_bounds__(256) void final_add_relu(
    const unsigned short* __restrict__ y3, const float* __restrict__ scale,
    const float* __restrict__ shift, const float* __restrict__ x,
    float* __restrict__ outp)
{
    size_t e = ((size_t)blockIdx.x * 256 + threadIdx.x) * 4;
    int c = (int)((e >> 14) & 255);
    ushort4 yv = *(const ushort4*)&y3[e];
    float4 xv = *(const float4*)&x[e];
    float sc = scale[c], sh = shift[c];
    float4 o;
    o.x = fmaxf(fmaf(sc, bf2f(yv.x), sh) + xv.x, 0.f);
    o.y = fmaxf(fmaf(sc, bf2f(yv.y), sh) + xv.y, 0.f);
    o.z = fmaxf(fmaf(sc, bf2f(yv.z), sh) + xv.z, 0.f);
    o.w = fmaxf(fmaf(sc, bf2f(yv.w), sh) + xv.w, 0.f);
    *(float4*)&outp[e] = o;
}

extern "C" void kernel_launch(void* const* d_in, const int* in_sizes, int n_in,
                              void* d_out, int out_size, void* d_ws, size_t ws_size,
                              hipStream_t stream)
{
    const float* x     = (const float*)d_in[0];
    const float* w1    = (const float*)d_in[1];
    const float* g1    = (const float*)d_in[2];
    const float* b1    = (const float*)d_in[3];
    const float* wq    = (const float*)d_in[4];
    const float* bq    = (const float*)d_in[5];
    const float* wk    = (const float*)d_in[6];
    const float* bk    = (const float*)d_in[7];
    const float* wv    = (const float*)d_in[8];
    const float* bv    = (const float*)d_in[9];
    const float* gamma = (const float*)d_in[10];
    const float* g2    = (const float*)d_in[11];
    const float* b2    = (const float*)d_in[12];
    const float* w3    = (const float*)d_in[13];
    const float* g3    = (const float*)d_in[14];
    const float* b3    = (const float*)d_in[15];
    float* out = (float*)d_out;

    char* wsb = (char*)d_ws;
    unsigned short* y1b = (unsigned short*)wsb;                        // 0-32 (later y3b)
    unsigned short* xt  = (unsigned short*)(wsb + ((size_t)32 << 20)); // 32-64 (later upn)
    unsigned short* accPb = (unsigned short*)wsb;                      // 0-16 during attn (bf16)
    unsigned short* hsb = (unsigned short*)(wsb + ((size_t)74 << 20)); // 74-82 (bf16 c-major)
    unsigned short* h2tb = (unsigned short*)(wsb + ((size_t)64 << 20));// 64-72
    float* psum2   = (float*)(wsb + ((size_t)72 << 20));               // 72-73 (BN2 partials)
    float* psumsq2 = (float*)(wsb + ((size_t)73 << 20));               // 73-74
    unsigned short* vbb = (unsigned short*)(wsb + ((size_t)82 << 20)); // 82-90 (key-permuted)
    unsigned short* hst = (unsigned short*)(wsb + ((size_t)90 << 20)); // 90-98
    unsigned short* qkT = (unsigned short*)(wsb + ((size_t)98 << 20)); // 98-100
    unsigned short* w1b = (unsigned short*)(wsb + ((size_t)100 << 20));
    unsigned short* wvb  = w1b + 65536;
    unsigned short* w3b  = wvb + 65536;
    unsigned short* wqkb = w3b + 65536;
    float* bqk = (float*)(wqkb + 16384);
    float2* mzP = (float2*)(wsb + ((size_t)100 << 20) + ((size_t)512 << 10));
    float* psumC   = (float*)(wsb + ((size_t)102 << 20));              // 102-103 (conv stats)
    float* psumsqC = (float*)(wsb + ((size_t)103 << 20));              // 103-104
    float* sc1 = (float*)(wsb + ((size_t)104 << 20)); float* sh1 = sc1 + 256;
    float* sc2 = sh1 + 256;      float* sh2 = sc2 + 256;
    float* sc3 = sh2 + 256;      float* sh3 = sc3 + 256;
    unsigned short* y3b = y1b;
    unsigned short* upn = xt;

    cvt_weights<<<256, 256, 0, stream>>>(w1, wq, wk, wv, w3, bq, bk,
                                         w1b, wqkb, wvb, w3b, bqk);
    transpose_cvt<<<dim3(256, 4, 4), 256, 0, stream>>>(x, xt, 16384);

    // net1: conv1 (MFMA, gl_lds staging, stats fused) -> BN1 -> BN+ReLU+down
    gemm_mfma<128, 2, 0, 1><<<dim3(128, 2, 4), 256, 0, stream>>>(
        w1b, xt, nullptr, y1b, psumC, psumsqC, 16384, 256);
    bn_finalize_ch<<<256, 256, 0, stream>>>(psumC, psumsqC, g1, b1, sc1, sh1,
                                            1.f / 65536.f, 1024);
    bnrelu_down<<<dim3(16, 256, 4), 256, 0, stream>>>(y1b, sc1, sh1, hsb);
    transpose_bf16<<<dim3(64, 4, 4), 256, 0, stream>>>(hsb, hst, 4096);

    // net2: merged qk projection + permuted v projection + split-K attention
    gemm_mfma<64, 1, 0, 0><<<dim3(32, 1, 4), 256, 0, stream>>>(
        wqkb, hst, bqk, qkT, nullptr, nullptr, 4096, 64);
    gemm_mfma<128, 2, 1, 0><<<dim3(32, 2, 4), 256, 0, stream>>>(
        wvb, hst, bv, vbb, nullptr, nullptr, 4096, 256);
    attn_partial<<<dim3(32, 2, 4), 512, 0, stream>>>(qkT, vbb, accPb, mzP);
    attn_combine_stats<<<dim3(256, 4), 256, 0, stream>>>(accPb, mzP, hst, gamma,
                                                         h2tb, psum2, psumsq2);

    // net2 tail: BN2 finalize (parallel) + ReLU fused into upsample
    bn_finalize_ch<<<256, 256, 0, stream>>>(psum2, psumsq2, g2, b2, sc2, sh2,
                                            1.f / 16384.f, 1024);
    upsample_bnrelu<<<dim3(1024, 4), 256, 0, stream>>>(h2tb, sc2, sh2, upn);

    // net3: conv3 (MFMA, gl_lds staging, stats fused) -> BN3 -> residual + ReLU
    gemm_mfma<128, 2, 0, 1><<<dim3(128, 2, 4), 256, 0, stream>>>(
        w3b, upn, nullptr, y3b, psumC, psumsqC, 16384, 256);
    bn_finalize_ch<<<256, 256, 0, stream>>>(psumC, psumsqC, g3, b3, sc3, sh3,
                                            1.f / 65536.f, 1024);
    final_add_relu<<<16384, 256, 0, stream>>>(y3b, sc3, sh3, x, out);
}